// Round 7
// baseline (176.570 us; speedup 1.0000x reference)
//
#include <hip/hip_runtime.h>

#define DEV __device__ __forceinline__

typedef __bf16 bf16x8 __attribute__((ext_vector_type(8)));
typedef __bf16 bf16x4 __attribute__((ext_vector_type(4)));
typedef float floatx4 __attribute__((ext_vector_type(4)));

// async 16B/lane global->LDS; HW writes LDS at (uniform base + lane*16)
DEV void async16(const __bf16* g, __bf16* l) {
  __builtin_amdgcn_global_load_lds((const __attribute__((address_space(1))) void*)g,
                                   (__attribute__((address_space(3))) void*)l, 16, 0, 0);
}

// ---------------- K0: fused prep: cvt weights + pool ctx + transpose x + zero stats ----
__global__ __launch_bounds__(256)
void prep_kernel(const float* __restrict__ Wq, const float* __restrict__ Wdy,
                 const float* __restrict__ ctx, const float* __restrict__ x,
                 __bf16* __restrict__ wqb, __bf16* __restrict__ wdyb,
                 float* __restrict__ kctx, __bf16* __restrict__ xt,
                 float* __restrict__ stats) {
  __shared__ float tile[64][65];
  int bid = blockIdx.x, t = threadIdx.x;
  if (bid < 256) {                       // weight cvt
    int i = bid * 256 + t;
    wqb[i]  = (__bf16)Wq[i];
    wdyb[i] = (__bf16)Wdy[i];
  } else if (bid < 512) {                // pool ctx 56x56 -> 7x7, one wave per (b,c)
    int bc = (bid - 256) * 4 + (t >> 6);
    const float* src = ctx + (size_t)bc * (56 * 56);
    int w = t & 63;
#pragma unroll
    for (int pi = 0; pi < 7; ++pi) {
      float s = 0.f;
      if (w < 56) {
#pragma unroll
        for (int di = 0; di < 8; ++di) s += src[(pi * 8 + di) * 56 + w];
      }
      s += __shfl_down(s, 4);
      s += __shfl_down(s, 2);
      s += __shfl_down(s, 1);
      if (w < 56 && (w & 7) == 0)
        kctx[(size_t)bc * 49 + pi * 7 + (w >> 3)] = s * (1.f / 64.f);
    }
  } else if (bid < 1536) {               // XT[b][n][c] = bf16(x[b][c][n])
    int idx = bid - 512;
    int b = idx >> 8, c0 = ((idx >> 6) & 3) * 64, n0 = (idx & 63) * 64;
    int lane = t & 63, rg = t >> 6;
    const float* src = x + ((size_t)b * 256 + c0) * 4096 + n0;
    for (int i = rg; i < 64; i += 4) tile[i][lane] = src[(size_t)i * 4096 + lane];
    __syncthreads();
    __bf16* dst = xt + ((size_t)b * 4096 + n0) * 256 + c0;
    for (int i = rg; i < 64; i += 4) dst[(size_t)i * 256 + lane] = (__bf16)tile[lane][i];
  } else {                               // zero LN stats (32768 floats)
    int base = (bid - 1536) * 1024 + t * 4;
    *(float4*)&stats[base] = make_float4(0.f, 0.f, 0.f, 0.f);
  }
}

// ---------------- K2: kf = LN(Wk @ kctx) per (b,l) ----------------
__global__ __launch_bounds__(256)
void kf_ln_kernel(const float* __restrict__ kctx, const float* __restrict__ Wk,
                  const float* __restrict__ gk, const float* __restrict__ bk,
                  float* __restrict__ kf) {
  int b = blockIdx.x / 49, l = blockIdx.x % 49;
  __shared__ float xs[256];
  __shared__ float r1[4], r2[4];
  int o = threadIdx.x;
  xs[o] = kctx[((size_t)b * 256 + o) * 49 + l];
  __syncthreads();
  const float* wrow = Wk + (size_t)o * 256;
  float acc = 0.f;
#pragma unroll 8
  for (int c = 0; c < 256; c += 4) {
    float4 wv = *(const float4*)(wrow + c);
    acc += wv.x * xs[c] + wv.y * xs[c + 1] + wv.z * xs[c + 2] + wv.w * xs[c + 3];
  }
  float s1 = acc, s2 = acc * acc;
#pragma unroll
  for (int off = 32; off > 0; off >>= 1) {
    s1 += __shfl_down(s1, off);
    s2 += __shfl_down(s2, off);
  }
  int wv_ = o >> 6, ln = o & 63;
  if (ln == 0) { r1[wv_] = s1; r2[wv_] = s2; }
  __syncthreads();
  float mu  = (r1[0] + r1[1] + r1[2] + r1[3]) * (1.f / 256.f);
  float var = (r2[0] + r2[1] + r2[2] + r2[3]) * (1.f / 256.f) - mu * mu;
  float rstd = rsqrtf(var + 1e-6f);
  kf[((size_t)b * 256 + o) * 49 + l] = (acc - mu) * rstd * gk[o] + bk[o];
}

// ------- K2b: kfpT[bg][m(80)][d(64)] = bf16( sum_l kf[b][g*64+d][l] * Wproj[m][l] ) -------
__global__ __launch_bounds__(256)
void kfp_kernel(const float* __restrict__ kf, const float* __restrict__ Wproj,
                __bf16* __restrict__ kfpT) {
  int bg = blockIdx.x; int b = bg >> 2, g = bg & 3;
  int m0 = blockIdx.y * 16;
  __shared__ float kfs[64][50];
  __shared__ float wps[16][50];
  int t = threadIdx.x;
  for (int i = t; i < 64 * 49; i += 256) {
    int d = i / 49, l = i % 49;
    kfs[d][l] = kf[((size_t)b * 256 + g * 64 + d) * 49 + l];
  }
  for (int i = t; i < 16 * 49; i += 256) {
    int m = i / 49, l = i % 49;
    wps[m][l] = (m0 + m < 74) ? Wproj[(m0 + m) * 49 + l] : 0.f;
  }
  __syncthreads();
  for (int i = t; i < 64 * 16; i += 256) {
    int d = i >> 4, m = i & 15;
    float s = 0.f;
    if (m0 + m < 74) {
#pragma unroll 7
      for (int l = 0; l < 49; ++l) s += kfs[d][l] * wps[m][l];
    }
    kfpT[(size_t)bg * 5120 + (m0 + m) * 64 + d] = (__bf16)s;
  }
}

// ---------------- K3: bf16 MFMA 1x1 conv, single-shot K=256 staging ----------------
// LDS [kc=8][ks=4][m=128][8]: global_load_lds writes lane-contiguous 16B; ds_read_b128
// frag fetch at 16B lane stride = conflict-free. One barrier, no K-loop.
// MODE 0: B = XT[b][n][256]; out qT[b][n][o] bf16 + LN stats atomics.
// MODE 1: B = midT planar [b*4+g][n][64]; out fp32 [o][n] + BN affine.
template <int MODE>
__global__ __launch_bounds__(256)
void conv_mfma_kernel(const __bf16* __restrict__ Wb, const __bf16* __restrict__ Xin,
                      void* __restrict__ Yout, float* __restrict__ stats,
                      const float* __restrict__ bn_g, const float* __restrict__ bn_b) {
  __shared__ __bf16 As[8][4][128][8];   // 64 KB
  __shared__ __bf16 Bs[8][4][128][8];   // 64 KB
  int b  = blockIdx.z;
  int n0 = blockIdx.x * 128;
  int o0 = blockIdx.y * 128;
  int t = threadIdx.x;
  int lane = t & 63, wv = t >> 6;
  // ---- stage everything asynchronously (32 instr/wave, all in flight) ----
#pragma unroll
  for (int i = 0; i < 16; ++i) {
    int u = wv * 16 + i;                       // 0..63
    int mh = u & 1, ks = (u >> 1) & 3, kc = u >> 3;
    int k8 = kc * 32 + ks * 8;
    const __bf16* ga = Wb + (size_t)(o0 + mh * 64 + lane) * 256 + k8;
    async16(ga, &As[kc][ks][mh * 64][0]);
    const __bf16* gb;
    if (MODE == 0) {
      gb = Xin + ((size_t)b * 4096 + n0 + mh * 64 + lane) * 256 + k8;
    } else {
      int g = k8 >> 6, c64 = k8 & 63;
      gb = Xin + ((size_t)(b * 4 + g) * 4096 + n0 + mh * 64 + lane) * 64 + c64;
    }
    async16(gb, &Bs[kc][ks][mh * 64][0]);
  }
  __syncthreads();
  // ---- compute: 8 kc x 16 MFMA per wave ----
  int mq = (wv & 1) * 64, nq = (wv >> 1) * 64;
  int col = lane & 15, quad = lane >> 4;
  floatx4 acc[4][4];
#pragma unroll
  for (int i = 0; i < 4; ++i)
#pragma unroll
    for (int j = 0; j < 4; ++j) acc[i][j] = {0.f, 0.f, 0.f, 0.f};
#pragma unroll
  for (int kc = 0; kc < 8; ++kc) {
    bf16x8 fa[4], fb[4];
#pragma unroll
    for (int i = 0; i < 4; ++i) fa[i] = *(const bf16x8*)&As[kc][quad][mq + i * 16 + col][0];
#pragma unroll
    for (int j = 0; j < 4; ++j) fb[j] = *(const bf16x8*)&Bs[kc][quad][nq + j * 16 + col][0];
#pragma unroll
    for (int i = 0; i < 4; ++i)
#pragma unroll
      for (int j = 0; j < 4; ++j)
        acc[i][j] = __builtin_amdgcn_mfma_f32_16x16x32_bf16(fa[i], fb[j], acc[i][j], 0, 0, 0);
  }
  // ---- epilogue ----
  if (MODE == 0) {
    __bf16* QT = (__bf16*)Yout + (size_t)b * 4096 * 256;
    float s_j[4] = {0.f, 0.f, 0.f, 0.f}, q_j[4] = {0.f, 0.f, 0.f, 0.f};
#pragma unroll
    for (int i = 0; i < 4; ++i) {
#pragma unroll
      for (int j = 0; j < 4; ++j) {
        int o = o0 + mq + i * 16 + quad * 4;
        int n = n0 + nq + j * 16 + col;
        __bf16 pk[4];
#pragma unroll
        for (int r = 0; r < 4; ++r) {
          float v = acc[i][j][r];
          s_j[j] += v; q_j[j] += v * v;
          pk[r] = (__bf16)v;
        }
        *(bf16x4*)&QT[(size_t)n * 256 + o] = *(bf16x4*)pk;
      }
    }
#pragma unroll
    for (int j = 0; j < 4; ++j) {
      float s = s_j[j], qq = q_j[j];
      s  += __shfl_down(s, 32);  s  += __shfl_down(s, 16);
      qq += __shfl_down(qq, 32); qq += __shfl_down(qq, 16);
      if (quad == 0) {
        int n = n0 + nq + j * 16 + col;
        atomicAdd(&stats[(size_t)b * 4096 + n], s);
        atomicAdd(&stats[16384 + (size_t)b * 4096 + n], qq);
      }
    }
  } else {
    float* Yf = (float*)Yout + (size_t)b * 256 * 4096;
#pragma unroll
    for (int i = 0; i < 4; ++i) {
#pragma unroll
      for (int r = 0; r < 4; ++r) {
        int o = o0 + mq + i * 16 + quad * 4 + r;
        float scale = bn_g[o] * 0.9999950000374997f;  // rsqrt(1 + 1e-5)
        float shift = bn_b[o];
        float* yrow = Yf + (size_t)o * 4096 + n0 + nq + col;
#pragma unroll
        for (int j = 0; j < 4; ++j) yrow[j * 16] = acc[i][j][r] * scale + shift;
      }
    }
  }
}

// ---------------- K4: attn = softmax(LN(q)^T kfp + rpb), MFMA QK, n-major output ----------
DEV int rep_idx(int p, int kc, int t1, int sub) {
  return p < kc ? p : (p < t1 ? kc : p - sub);
}

template <int KK>
DEV void softmax_write(const float* wms, const float* rpb_s, float* __restrict__ attnL,
                       int bg, int n_glob, int t) {
  constexpr int CNT = KK * KK;
  constexpr int RS  = 2 * KK - 1;
  constexpr int KC  = KK / 2;
  constexpr int T1  = KC + (64 - KK + 1);
  constexpr int SUB = 64 - KK;
  constexpr int MLO = (KK == 5) ? 0 : 25;
  constexpr int WR  = (CNT + 3) / 4;
  int h = n_glob >> 6, w = n_glob & 63;
  int rh = rep_idx(63 - h, KC, T1, SUB);
  int rw = rep_idx(63 - w, KC, T1, SUB);
  float vals[WR * 4];
#pragma unroll
  for (int m = 0; m < WR * 4; ++m) vals[m] = 0.f;
  float mx = -1e30f;
#pragma unroll
  for (int m = 0; m < CNT; ++m) {
    int ki = m / KK, kj = m % KK;
    float v = wms[t * 81 + MLO + m] + rpb_s[(rh + ki) * RS + rw + kj];
    vals[m] = v; mx = fmaxf(mx, v);
  }
  float ssum = 0.f;
#pragma unroll
  for (int m = 0; m < CNT; ++m) { float e = __expf(vals[m] - mx); vals[m] = e; ssum += e; }
  float inv = 1.f / ssum;
#pragma unroll
  for (int m = 0; m < CNT; ++m) vals[m] *= inv;
  float* ap = attnL + ((size_t)bg * 4096 + n_glob) * 52;
#pragma unroll
  for (int i = 0; i < WR; ++i) *(float4*)(ap + i * 4) = *(float4*)&vals[i * 4];
}

__global__ __launch_bounds__(256)
void attn_kernel(const __bf16* __restrict__ qT, const float* __restrict__ stats,
                 const float* __restrict__ gq, const float* __restrict__ bq,
                 const __bf16* __restrict__ kfpT, const float* __restrict__ rpb1,
                 const float* __restrict__ rpb2, float* __restrict__ attnL) {
  __shared__ uint32_t smem4[10368];   // A_s[128][72]bf16 + B_s[80][72]bf16, reused as wms[128][81]f32
  __shared__ float rpb_s[169];
  __bf16* A_s = (__bf16*)smem4;
  __bf16* B_s = (__bf16*)smem4 + 9216;
  float* wms  = (float*)smem4;
  int bg = blockIdx.x; int b = bg >> 2, g = bg & 3;   // x=bg: XCD = bg%8 (L2 pinning)
  int n0 = blockIdx.y * 128;
  int t = threadIdx.x;
  // stage A = LN(q)*SCALE as bf16 [n][64] (+8 pad)
  for (int idx = t; idx < 1024; idx += 256) {
    int n = idx >> 3, d8 = idx & 7;
    int ng = n0 + n;
    float s  = stats[(size_t)b * 4096 + ng];
    float ss = stats[16384 + (size_t)b * 4096 + ng];
    float mu = s * (1.f / 256.f);
    float rs = rsqrtf(ss * (1.f / 256.f) - mu * mu + 1e-6f);
    bf16x8 raw = *(const bf16x8*)&qT[((size_t)b * 4096 + ng) * 256 + g * 64 + d8 * 8];
    __bf16 tmp[8];
#pragma unroll
    for (int e = 0; e < 8; ++e) {
      int d = g * 64 + d8 * 8 + e;
      tmp[e] = (__bf16)((((float)raw[e]) - mu) * rs * (gq[d] * 0.125f) + bq[d] * 0.125f);
    }
    *(bf16x8*)&A_s[n * 72 + d8 * 8] = *(bf16x8*)tmp;
  }
  // stage B = kfpT [m=80][64] (+8 pad)
  for (int idx = t; idx < 640; idx += 256)
    *(bf16x8*)&B_s[(idx >> 3) * 72 + (idx & 7) * 8] = *(const bf16x8*)&kfpT[(size_t)bg * 5120 + idx * 8];
  if (g < 2) { for (int i = t; i <  81; i += 256) rpb_s[i] = rpb1[g * 81 + i]; }
  else       { for (int i = t; i < 169; i += 256) rpb_s[i] = rpb2[(g - 2) * 169 + i]; }
  __syncthreads();
  // MFMA: M=128(n) x N=80(m) x K=64; wave wv owns m-tiles {2wv,2wv+1}
  int lane = t & 63, wv = t >> 6;
  int col = lane & 15, quad = lane >> 4;
  floatx4 acc[2][5];
#pragma unroll
  for (int mi = 0; mi < 2; ++mi)
#pragma unroll
    for (int nt = 0; nt < 5; ++nt) acc[mi][nt] = {0.f, 0.f, 0.f, 0.f};
  bf16x8 fa[2][2], fb[2][5];
#pragma unroll
  for (int ks = 0; ks < 2; ++ks) {
#pragma unroll
    for (int mi = 0; mi < 2; ++mi)
      fa[ks][mi] = *(const bf16x8*)&A_s[((wv * 2 + mi) * 16 + col) * 72 + ks * 32 + quad * 8];
#pragma unroll
    for (int nt = 0; nt < 5; ++nt)
      fb[ks][nt] = *(const bf16x8*)&B_s[(nt * 16 + col) * 72 + ks * 32 + quad * 8];
  }
#pragma unroll
  for (int ks = 0; ks < 2; ++ks)
#pragma unroll
    for (int mi = 0; mi < 2; ++mi)
#pragma unroll
      for (int nt = 0; nt < 5; ++nt)
        acc[mi][nt] = __builtin_amdgcn_mfma_f32_16x16x32_bf16(fa[ks][mi], fb[ks][nt], acc[mi][nt], 0, 0, 0);
  __syncthreads();   // before overwriting A_s/B_s with wms
#pragma unroll
  for (int mi = 0; mi < 2; ++mi)
#pragma unroll
    for (int nt = 0; nt < 5; ++nt)
#pragma unroll
      for (int r = 0; r < 4; ++r)
        wms[((wv * 2 + mi) * 16 + quad * 4 + r) * 81 + nt * 16 + col] = acc[mi][nt][r];
  __syncthreads();
  if (t < 128) {
    int n_glob = n0 + t;
    if (g < 2) softmax_write<5>(wms, rpb_s, attnL, bg, n_glob, t);
    else       softmax_write<7>(wms, rpb_s, attnL, bg, n_glob, t);
  }
}

// ------- K5: na2d AV with LDS-staged XT slab -------
// block = (bg, 4-h slab, ch-half). LDS xs[ROWS<=10][64 w][40(32+8pad) ch] bf16.
// thread (w = t>>2, cg = t&3) computes 4 h x 8 ch.
template <int KK>
DEV void na2d_body(const float* __restrict__ attnL, const __bf16* __restrict__ XT,
                   __bf16* __restrict__ midT, __bf16* xs, int bg, int h0, int chalf, int t) {
  constexpr int CNT = KK * KK, KC = KK / 2, SMAX = 64 - KK;
  constexpr int ROWS = KK + 3;
  constexpr int WR = (CNT + 3) / 4;
  int b = bg >> 2, g = bg & 3;
  int si0 = min(max(h0 - KC, 0), SMAX);
  // stage ROWS rows of the 32-ch half into LDS
  {
    int sn = t >> 2, sc = t & 3;
    const __bf16* src = XT + ((size_t)b * 4096 + sn) * 256 + g * 64 + chalf * 32 + sc * 8;
#pragma unroll
    for (int r = 0; r < ROWS; ++r) {
      int gr = min(si0 + r, 63);
      *(bf16x8*)&xs[(r * 64 + sn) * 40 + sc * 8] = *(const bf16x8*)(src + (size_t)gr * 64 * 256);
    }
  }
  __syncthreads();
  int w = t >> 2, cg = t & 3;
  int sj = min(max(w - KC, 0), SMAX);
#pragma unroll
  for (int h4 = 0; h4 < 4; ++h4) {
    int h = h0 + h4;
    int base = min(max(h - KC, 0), SMAX) - si0;
    float av[WR * 4];
    const float* ap = attnL + ((size_t)bg * 4096 + h * 64 + w) * 52;
#pragma unroll
    for (int i = 0; i < WR; ++i) *(float4*)&av[i * 4] = *(const float4*)(ap + i * 4);
    float acc[8] = {};
#pragma unroll
    for (int p = 0; p < KK; ++p) {
      const __bf16* xr = &xs[((base + p) * 64 + sj) * 40 + cg * 8];
#pragma unroll
      for (int q = 0; q < KK; ++q) {
        bf16x8 v = *(const bf16x8*)(xr + q * 40);
        float a = av[p * KK + q];
#pragma unroll
        for (int e = 0; e < 8; ++e) acc[e] += a * (float)v[e];
      }
    }
    __bf16 hv[8];
#pragma unroll
    for (int e = 0; e < 8; ++e) hv[e] = (__bf16)acc[e];
    *(bf16x8*)&midT[((size_t)bg * 4096 + h * 64 + w) * 64 + chalf * 32 + cg * 8] = *(bf16x8*)hv;
  }
}

__global__ __launch_bounds__(256)
void na2d_kernel(const float* __restrict__ attnL, const __bf16* __restrict__ XT,
                 __bf16* __restrict__ midT) {
  __shared__ __bf16 xs[10 * 64 * 40];   // 51.2 KB
  int bg = blockIdx.x, h0 = blockIdx.y * 4, chalf = blockIdx.z, t = threadIdx.x;
  if ((bg & 3) < 2) na2d_body<5>(attnL, XT, midT, xs, bg, h0, chalf, t);
  else              na2d_body<7>(attnL, XT, midT, xs, bg, h0, chalf, t);
}

// ---------------- launch ----------------
extern "C" void kernel_launch(void* const* d_in, const int* in_sizes, int n_in,
                              void* d_out, int out_size, void* d_ws, size_t ws_size,
                              hipStream_t stream) {
  const float* x     = (const float*)d_in[0];
  const float* ctx   = (const float*)d_in[1];
  const float* Wq    = (const float*)d_in[2];
  const float* gq    = (const float*)d_in[3];
  const float* bq    = (const float*)d_in[4];
  const float* Wk    = (const float*)d_in[5];
  const float* gk    = (const float*)d_in[6];
  const float* bk    = (const float*)d_in[7];
  const float* Wproj = (const float*)d_in[8];
  const float* rpb1  = (const float*)d_in[9];
  const float* rpb2  = (const float*)d_in[10];
  const float* Wdy   = (const float*)d_in[11];
  const float* bn_g  = (const float*)d_in[12];
  const float* bn_b  = (const float*)d_in[13];
  float* out = (float*)d_out;

  float* ws     = (float*)d_ws;
  float* kctx   = ws;                          // 50176 f
  float* kf     = kctx + 50176;                // 50176 f
  float* stats  = kf + 50176;                  // 32768 f (sum | sumsq planes)
  float* attnL  = stats + 32768;               // 16*4096*52 = 3407872 f
  __bf16* wqb   = (__bf16*)(attnL + 3407872);  // 65536 bf16
  __bf16* wdyb  = wqb + 65536;                 // 65536 bf16
  __bf16* kfpT  = wdyb + 65536;                // 16*80*64 = 81920 bf16
  __bf16* XT    = kfpT + 81920;                // 4194304 bf16
  __bf16* qT    = XT + 4194304;                // 4194304 bf16
  __bf16* midT  = qT + 4194304;                // 4194304 bf16 (planar [bg][n][64])

  prep_kernel<<<dim3(1568), dim3(256), 0, stream>>>(Wq, Wdy, ctx, x, wqb, wdyb, kctx, XT, stats);
  kf_ln_kernel<<<dim3(196), dim3(256), 0, stream>>>(kctx, Wk, gk, bk, kf);
  kfp_kernel<<<dim3(16, 5), dim3(256), 0, stream>>>(kf, Wproj, kfpT);
  conv_mfma_kernel<0><<<dim3(32, 2, 4), dim3(256), 0, stream>>>(wqb, XT, qT, stats, nullptr, nullptr);
  attn_kernel<<<dim3(16, 32), dim3(256), 0, stream>>>(qT, stats, gq, bq, kfpT, rpb1, rpb2, attnL);
  na2d_kernel<<<dim3(16, 16, 2), dim3(256), 0, stream>>>(attnL, XT, midT);
  conv_mfma_kernel<1><<<dim3(32, 2, 4), dim3(256), 0, stream>>>(wdyb, midT, out, nullptr, bn_g, bn_b);
}

// Round 8
// 164.661 us; speedup vs baseline: 1.0723x; 1.0723x over previous
//
#include <hip/hip_runtime.h>

#define DEV __device__ __forceinline__

typedef __bf16 bf16x8 __attribute__((ext_vector_type(8)));
typedef __bf16 bf16x4 __attribute__((ext_vector_type(4)));
typedef float floatx4 __attribute__((ext_vector_type(4)));

// ---------------- K0: fused prep: cvt weights + pool ctx + transpose x + zero stats ----
__global__ __launch_bounds__(256)
void prep_kernel(const float* __restrict__ Wq, const float* __restrict__ Wdy,
                 const float* __restrict__ ctx, const float* __restrict__ x,
                 __bf16* __restrict__ wqb, __bf16* __restrict__ wdyb,
                 float* __restrict__ kctx, __bf16* __restrict__ xt,
                 float* __restrict__ stats) {
  __shared__ float tile[64][65];
  int bid = blockIdx.x, t = threadIdx.x;
  if (bid < 256) {                       // weight cvt
    int i = bid * 256 + t;
    wqb[i]  = (__bf16)Wq[i];
    wdyb[i] = (__bf16)Wdy[i];
  } else if (bid < 512) {                // pool ctx 56x56 -> 7x7, one wave per (b,c)
    int bc = (bid - 256) * 4 + (t >> 6);
    const float* src = ctx + (size_t)bc * (56 * 56);
    int w = t & 63;
#pragma unroll
    for (int pi = 0; pi < 7; ++pi) {
      float s = 0.f;
      if (w < 56) {
#pragma unroll
        for (int di = 0; di < 8; ++di) s += src[(pi * 8 + di) * 56 + w];
      }
      s += __shfl_down(s, 4);
      s += __shfl_down(s, 2);
      s += __shfl_down(s, 1);
      if (w < 56 && (w & 7) == 0)
        kctx[(size_t)bc * 49 + pi * 7 + (w >> 3)] = s * (1.f / 64.f);
    }
  } else if (bid < 1536) {               // XT[b][n][c] = bf16(x[b][c][n])
    int idx = bid - 512;
    int b = idx >> 8, c0 = ((idx >> 6) & 3) * 64, n0 = (idx & 63) * 64;
    int lane = t & 63, rg = t >> 6;
    const float* src = x + ((size_t)b * 256 + c0) * 4096 + n0;
    for (int i = rg; i < 64; i += 4) tile[i][lane] = src[(size_t)i * 4096 + lane];
    __syncthreads();
    __bf16* dst = xt + ((size_t)b * 4096 + n0) * 256 + c0;
    for (int i = rg; i < 64; i += 4) dst[(size_t)i * 256 + lane] = (__bf16)tile[lane][i];
  } else {                               // zero LN stats (32768 floats)
    int base = (bid - 1536) * 1024 + t * 4;
    *(float4*)&stats[base] = make_float4(0.f, 0.f, 0.f, 0.f);
  }
}

// ---------------- K2: kf = LN(Wk @ kctx) per (b,l) ----------------
__global__ __launch_bounds__(256)
void kf_ln_kernel(const float* __restrict__ kctx, const float* __restrict__ Wk,
                  const float* __restrict__ gk, const float* __restrict__ bk,
                  float* __restrict__ kf) {
  int b = blockIdx.x / 49, l = blockIdx.x % 49;
  __shared__ float xs[256];
  __shared__ float r1[4], r2[4];
  int o = threadIdx.x;
  xs[o] = kctx[((size_t)b * 256 + o) * 49 + l];
  __syncthreads();
  const float* wrow = Wk + (size_t)o * 256;
  float acc = 0.f;
#pragma unroll 8
  for (int c = 0; c < 256; c += 4) {
    float4 wv = *(const float4*)(wrow + c);
    acc += wv.x * xs[c] + wv.y * xs[c + 1] + wv.z * xs[c + 2] + wv.w * xs[c + 3];
  }
  float s1 = acc, s2 = acc * acc;
#pragma unroll
  for (int off = 32; off > 0; off >>= 1) {
    s1 += __shfl_down(s1, off);
    s2 += __shfl_down(s2, off);
  }
  int wv_ = o >> 6, ln = o & 63;
  if (ln == 0) { r1[wv_] = s1; r2[wv_] = s2; }
  __syncthreads();
  float mu  = (r1[0] + r1[1] + r1[2] + r1[3]) * (1.f / 256.f);
  float var = (r2[0] + r2[1] + r2[2] + r2[3]) * (1.f / 256.f) - mu * mu;
  float rstd = rsqrtf(var + 1e-6f);
  kf[((size_t)b * 256 + o) * 49 + l] = (acc - mu) * rstd * gk[o] + bk[o];
}

// ------- K2b: kfpT[bg][m(80)][d(64)] = bf16( sum_l kf[b][g*64+d][l] * Wproj[m][l] ) -------
__global__ __launch_bounds__(256)
void kfp_kernel(const float* __restrict__ kf, const float* __restrict__ Wproj,
                __bf16* __restrict__ kfpT) {
  int bg = blockIdx.x; int b = bg >> 2, g = bg & 3;
  int m0 = blockIdx.y * 16;
  __shared__ float kfs[64][50];
  __shared__ float wps[16][50];
  int t = threadIdx.x;
  for (int i = t; i < 64 * 49; i += 256) {
    int d = i / 49, l = i % 49;
    kfs[d][l] = kf[((size_t)b * 256 + g * 64 + d) * 49 + l];
  }
  for (int i = t; i < 16 * 49; i += 256) {
    int m = i / 49, l = i % 49;
    wps[m][l] = (m0 + m < 74) ? Wproj[(m0 + m) * 49 + l] : 0.f;
  }
  __syncthreads();
  for (int i = t; i < 64 * 16; i += 256) {
    int d = i >> 4, m = i & 15;
    float s = 0.f;
    if (m0 + m < 74) {
#pragma unroll 7
      for (int l = 0; l < 49; ++l) s += kfs[d][l] * wps[m][l];
    }
    kfpT[(size_t)bg * 5120 + (m0 + m) * 64 + d] = (__bf16)s;
  }
}

// ---------------- K3: bf16 MFMA 1x1 conv (R6-proven K-loop version) ----------------
// MODE 0: B = XT[b][n][256] interleaved; out qT[b][n][o] bf16 + LN stats atomics.
// MODE 1: B = midT planar [b*4+g][n][64]; out fp32 [o][n] + BN affine.
template <int MODE>
__global__ __launch_bounds__(256, 2)
void conv_mfma_kernel(const __bf16* __restrict__ Wb, const __bf16* __restrict__ Xin,
                      void* __restrict__ Yout, float* __restrict__ stats,
                      const float* __restrict__ bn_g, const float* __restrict__ bn_b) {
  int b  = blockIdx.z;
  int n0 = blockIdx.x * 128;
  int o0 = blockIdx.y * 128;
  __shared__ __bf16 As[128 * 32];   // [m][k]
  __shared__ __bf16 Bs[128 * 32];   // [n][k]
  int t = threadIdx.x;
  int lane = t & 63, wv = t >> 6;
  int mq = (wv & 1) * 64, nq = (wv >> 1) * 64;
  int col = lane & 15, quad = lane >> 4;
  floatx4 acc[4][4];
#pragma unroll
  for (int i = 0; i < 4; ++i)
#pragma unroll
    for (int j = 0; j < 4; ++j) acc[i][j] = {0.f, 0.f, 0.f, 0.f};
  int sm = t >> 1, sk = (t & 1) << 4;
  for (int c0 = 0; c0 < 256; c0 += 32) {
    const __bf16* wsrc = Wb + (size_t)(o0 + sm) * 256 + c0 + sk;
    *(bf16x8*)&As[sm * 32 + sk]     = *(const bf16x8*)wsrc;
    *(bf16x8*)&As[sm * 32 + sk + 8] = *(const bf16x8*)(wsrc + 8);
    const __bf16* xsrc;
    if (MODE == 0) {
      xsrc = Xin + ((size_t)b * 4096 + n0 + sm) * 256 + c0 + sk;
    } else {
      int c = c0 + sk, g = c >> 6, c64 = c & 63;   // 16-elem load stays in-plane
      xsrc = Xin + (((size_t)(b * 4 + g)) * 4096 + n0 + sm) * 64 + c64;
    }
    *(bf16x8*)&Bs[sm * 32 + sk]     = *(const bf16x8*)xsrc;
    *(bf16x8*)&Bs[sm * 32 + sk + 8] = *(const bf16x8*)(xsrc + 8);
    __syncthreads();
    bf16x8 fa[4], fb[4];
#pragma unroll
    for (int i = 0; i < 4; ++i)
      fa[i] = *(const bf16x8*)&As[(mq + i * 16 + col) * 32 + quad * 8];
#pragma unroll
    for (int j = 0; j < 4; ++j)
      fb[j] = *(const bf16x8*)&Bs[(nq + j * 16 + col) * 32 + quad * 8];
#pragma unroll
    for (int i = 0; i < 4; ++i)
#pragma unroll
      for (int j = 0; j < 4; ++j)
        acc[i][j] = __builtin_amdgcn_mfma_f32_16x16x32_bf16(fa[i], fb[j], acc[i][j], 0, 0, 0);
    __syncthreads();
  }
  if (MODE == 0) {
    __bf16* QT = (__bf16*)Yout + (size_t)b * 4096 * 256;
    float s_j[4] = {0.f, 0.f, 0.f, 0.f}, q_j[4] = {0.f, 0.f, 0.f, 0.f};
#pragma unroll
    for (int i = 0; i < 4; ++i) {
#pragma unroll
      for (int j = 0; j < 4; ++j) {
        int o = o0 + mq + i * 16 + quad * 4;
        int n = n0 + nq + j * 16 + col;
        __bf16 pk[4];
#pragma unroll
        for (int r = 0; r < 4; ++r) {
          float v = acc[i][j][r];
          s_j[j] += v; q_j[j] += v * v;
          pk[r] = (__bf16)v;
        }
        *(bf16x4*)&QT[(size_t)n * 256 + o] = *(bf16x4*)pk;
      }
    }
#pragma unroll
    for (int j = 0; j < 4; ++j) {
      float s = s_j[j], qq = q_j[j];
      s  += __shfl_down(s, 32);  s  += __shfl_down(s, 16);
      qq += __shfl_down(qq, 32); qq += __shfl_down(qq, 16);
      if (quad == 0) {
        int n = n0 + nq + j * 16 + col;
        atomicAdd(&stats[(size_t)b * 4096 + n], s);
        atomicAdd(&stats[16384 + (size_t)b * 4096 + n], qq);
      }
    }
  } else {
    float* Yf = (float*)Yout + (size_t)b * 256 * 4096;
#pragma unroll
    for (int i = 0; i < 4; ++i) {
#pragma unroll
      for (int r = 0; r < 4; ++r) {
        int o = o0 + mq + i * 16 + quad * 4 + r;
        float scale = bn_g[o] * 0.9999950000374997f;  // rsqrt(1 + 1e-5)
        float shift = bn_b[o];
        float* yrow = Yf + (size_t)o * 4096 + n0 + nq + col;
#pragma unroll
        for (int j = 0; j < 4; ++j) yrow[j * 16] = acc[i][j][r] * scale + shift;
      }
    }
  }
}

// ---------------- K4: attn = softmax(LN(q)^T kfp + rpb), MFMA QK, bf16 n-major out ------
DEV int rep_idx(int p, int kc, int t1, int sub) {
  return p < kc ? p : (p < t1 ? kc : p - sub);
}

template <int KK>
DEV void softmax_write(const float* wms, const float* rpb_s, __bf16* __restrict__ attnL,
                       int bg, int n_glob, int t) {
  constexpr int CNT = KK * KK;
  constexpr int RS  = 2 * KK - 1;
  constexpr int KC  = KK / 2;
  constexpr int T1  = KC + (64 - KK + 1);
  constexpr int SUB = 64 - KK;
  constexpr int MLO = (KK == 5) ? 0 : 25;
  constexpr int PW  = (KK == 5) ? 32 : 56;    // padded width (multiple of 8)
  int h = n_glob >> 6, w = n_glob & 63;
  int rh = rep_idx(63 - h, KC, T1, SUB);
  int rw = rep_idx(63 - w, KC, T1, SUB);
  float vals[CNT];
  float mx = -1e30f;
#pragma unroll
  for (int m = 0; m < CNT; ++m) {
    int ki = m / KK, kj = m % KK;
    float v = wms[t * 81 + MLO + m] + rpb_s[(rh + ki) * RS + rw + kj];
    vals[m] = v; mx = fmaxf(mx, v);
  }
  float ssum = 0.f;
#pragma unroll
  for (int m = 0; m < CNT; ++m) { float e = __expf(vals[m] - mx); vals[m] = e; ssum += e; }
  float inv = 1.f / ssum;
  __bf16 hv[PW];
#pragma unroll
  for (int m = 0; m < PW; ++m) hv[m] = (__bf16)(m < CNT ? vals[m] * inv : 0.f);
  __bf16* ap = attnL + ((size_t)bg * 4096 + n_glob) * 56;
#pragma unroll
  for (int i = 0; i < PW / 8; ++i) *(bf16x8*)(ap + i * 8) = *(bf16x8*)&hv[i * 8];
}

__global__ __launch_bounds__(256)
void attn_kernel(const __bf16* __restrict__ qT, const float* __restrict__ stats,
                 const float* __restrict__ gq, const float* __restrict__ bq,
                 const __bf16* __restrict__ kfpT, const float* __restrict__ rpb1,
                 const float* __restrict__ rpb2, __bf16* __restrict__ attnL) {
  __shared__ uint32_t smem4[10368];   // A_s[128][72]bf16 + B_s[80][72]bf16, reused as wms[128][81]f32
  __shared__ float rpb_s[169];
  __bf16* A_s = (__bf16*)smem4;
  __bf16* B_s = (__bf16*)smem4 + 9216;
  float* wms  = (float*)smem4;
  int bg = blockIdx.x; int b = bg >> 2, g = bg & 3;   // x=bg: XCD = bg%8 (L2 pinning)
  int n0 = blockIdx.y * 128;
  int t = threadIdx.x;
  // stage A = LN(q)*SCALE as bf16 [n][64] (+8 pad)
  for (int idx = t; idx < 1024; idx += 256) {
    int n = idx >> 3, d8 = idx & 7;
    int ng = n0 + n;
    float s  = stats[(size_t)b * 4096 + ng];
    float ss = stats[16384 + (size_t)b * 4096 + ng];
    float mu = s * (1.f / 256.f);
    float rs = rsqrtf(ss * (1.f / 256.f) - mu * mu + 1e-6f);
    bf16x8 raw = *(const bf16x8*)&qT[((size_t)b * 4096 + ng) * 256 + g * 64 + d8 * 8];
    __bf16 tmp[8];
#pragma unroll
    for (int e = 0; e < 8; ++e) {
      int d = g * 64 + d8 * 8 + e;
      tmp[e] = (__bf16)((((float)raw[e]) - mu) * rs * (gq[d] * 0.125f) + bq[d] * 0.125f);
    }
    *(bf16x8*)&A_s[n * 72 + d8 * 8] = *(bf16x8*)tmp;
  }
  // stage B = kfpT [m=80][64] (+8 pad)
  for (int idx = t; idx < 640; idx += 256)
    *(bf16x8*)&B_s[(idx >> 3) * 72 + (idx & 7) * 8] = *(const bf16x8*)&kfpT[(size_t)bg * 5120 + idx * 8];
  if (g < 2) { for (int i = t; i <  81; i += 256) rpb_s[i] = rpb1[g * 81 + i]; }
  else       { for (int i = t; i < 169; i += 256) rpb_s[i] = rpb2[(g - 2) * 169 + i]; }
  __syncthreads();
  // MFMA: M=128(n) x N=80(m) x K=64; wave wv owns m-tiles {2wv,2wv+1}
  int lane = t & 63, wv = t >> 6;
  int col = lane & 15, quad = lane >> 4;
  floatx4 acc[2][5];
#pragma unroll
  for (int mi = 0; mi < 2; ++mi)
#pragma unroll
    for (int nt = 0; nt < 5; ++nt) acc[mi][nt] = {0.f, 0.f, 0.f, 0.f};
  bf16x8 fa[2][2], fb[2][5];
#pragma unroll
  for (int ks = 0; ks < 2; ++ks) {
#pragma unroll
    for (int mi = 0; mi < 2; ++mi)
      fa[ks][mi] = *(const bf16x8*)&A_s[((wv * 2 + mi) * 16 + col) * 72 + ks * 32 + quad * 8];
#pragma unroll
    for (int nt = 0; nt < 5; ++nt)
      fb[ks][nt] = *(const bf16x8*)&B_s[(nt * 16 + col) * 72 + ks * 32 + quad * 8];
  }
#pragma unroll
  for (int ks = 0; ks < 2; ++ks)
#pragma unroll
    for (int mi = 0; mi < 2; ++mi)
#pragma unroll
      for (int nt = 0; nt < 5; ++nt)
        acc[mi][nt] = __builtin_amdgcn_mfma_f32_16x16x32_bf16(fa[ks][mi], fb[ks][nt], acc[mi][nt], 0, 0, 0);
  __syncthreads();   // before overwriting A_s/B_s with wms
#pragma unroll
  for (int mi = 0; mi < 2; ++mi)
#pragma unroll
    for (int nt = 0; nt < 5; ++nt)
#pragma unroll
      for (int r = 0; r < 4; ++r)
        wms[((wv * 2 + mi) * 16 + quad * 4 + r) * 81 + nt * 16 + col] = acc[mi][nt][r];
  __syncthreads();
  if (t < 128) {
    int n_glob = n0 + t;
    if (g < 2) softmax_write<5>(wms, rpb_s, attnL, bg, n_glob, t);
    else       softmax_write<7>(wms, rpb_s, attnL, bg, n_glob, t);
  }
}

// ------- K5: na2d AV with LDS-staged XT slab; bf16 attn input -------
// block = (bg, 4-h slab, ch-half). LDS xs[ROWS<=10][64 w][40(32+8pad) ch] bf16.
// thread (w = t>>2, cg = t&3) computes 4 h x 8 ch.
template <int KK>
DEV void na2d_body(const __bf16* __restrict__ attnL, const __bf16* __restrict__ XT,
                   __bf16* __restrict__ midT, __bf16* xs, int bg, int h0, int chalf, int t) {
  constexpr int CNT = KK * KK, KC = KK / 2, SMAX = 64 - KK;
  constexpr int ROWS = KK + 3;
  constexpr int PW = (KK == 5) ? 32 : 56;
  int b = bg >> 2, g = bg & 3;
  int si0 = min(max(h0 - KC, 0), SMAX);
  // stage ROWS rows of the 32-ch half into LDS
  {
    int sn = t >> 2, sc = t & 3;
    const __bf16* src = XT + ((size_t)b * 4096 + sn) * 256 + g * 64 + chalf * 32 + sc * 8;
#pragma unroll
    for (int r = 0; r < ROWS; ++r) {
      int gr = min(si0 + r, 63);
      *(bf16x8*)&xs[(r * 64 + sn) * 40 + sc * 8] = *(const bf16x8*)(src + (size_t)gr * 64 * 256);
    }
  }
  __syncthreads();
  int w = t >> 2, cg = t & 3;
  int sj = min(max(w - KC, 0), SMAX);
#pragma unroll
  for (int h4 = 0; h4 < 4; ++h4) {
    int h = h0 + h4;
    int base = min(max(h - KC, 0), SMAX) - si0;
    bf16x8 avh[PW / 8];
    const __bf16* ap = attnL + ((size_t)bg * 4096 + h * 64 + w) * 56;
#pragma unroll
    for (int i = 0; i < PW / 8; ++i) avh[i] = *(const bf16x8*)(ap + i * 8);
    float av[CNT];
#pragma unroll
    for (int m = 0; m < CNT; ++m) av[m] = (float)avh[m / 8][m % 8];
    float acc[8] = {};
#pragma unroll
    for (int p = 0; p < KK; ++p) {
      const __bf16* xr = &xs[((base + p) * 64 + sj) * 40 + cg * 8];
#pragma unroll
      for (int q = 0; q < KK; ++q) {
        bf16x8 v = *(const bf16x8*)(xr + q * 40);
        float a = av[p * KK + q];
#pragma unroll
        for (int e = 0; e < 8; ++e) acc[e] += a * (float)v[e];
      }
    }
    __bf16 hv[8];
#pragma unroll
    for (int e = 0; e < 8; ++e) hv[e] = (__bf16)acc[e];
    *(bf16x8*)&midT[((size_t)bg * 4096 + h * 64 + w) * 64 + chalf * 32 + cg * 8] = *(bf16x8*)hv;
  }
}

__global__ __launch_bounds__(256)
void na2d_kernel(const __bf16* __restrict__ attnL, const __bf16* __restrict__ XT,
                 __bf16* __restrict__ midT) {
  __shared__ __bf16 xs[10 * 64 * 40];   // 51.2 KB
  int bg = blockIdx.x, h0 = blockIdx.y * 4, chalf = blockIdx.z, t = threadIdx.x;
  if ((bg & 3) < 2) na2d_body<5>(attnL, XT, midT, xs, bg, h0, chalf, t);
  else              na2d_body<7>(attnL, XT, midT, xs, bg, h0, chalf, t);
}

// ---------------- launch ----------------
extern "C" void kernel_launch(void* const* d_in, const int* in_sizes, int n_in,
                              void* d_out, int out_size, void* d_ws, size_t ws_size,
                              hipStream_t stream) {
  const float* x     = (const float*)d_in[0];
  const float* ctx   = (const float*)d_in[1];
  const float* Wq    = (const float*)d_in[2];
  const float* gq    = (const float*)d_in[3];
  const float* bq    = (const float*)d_in[4];
  const float* Wk    = (const float*)d_in[5];
  const float* gk    = (const float*)d_in[6];
  const float* bk    = (const float*)d_in[7];
  const float* Wproj = (const float*)d_in[8];
  const float* rpb1  = (const float*)d_in[9];
  const float* rpb2  = (const float*)d_in[10];
  const float* Wdy   = (const float*)d_in[11];
  const float* bn_g  = (const float*)d_in[12];
  const float* bn_b  = (const float*)d_in[13];
  float* out = (float*)d_out;

  float* ws     = (float*)d_ws;
  float* kctx   = ws;                          // 50176 f
  float* kf     = kctx + 50176;                // 50176 f
  float* stats  = kf + 50176;                  // 32768 f (sum | sumsq planes)
  __bf16* attnL = (__bf16*)(stats + 32768);    // 16*4096*56 = 3670016 bf16
  __bf16* wqb   = attnL + 3670016;             // 65536 bf16
  __bf16* wdyb  = wqb + 65536;                 // 65536 bf16
  __bf16* kfpT  = wdyb + 65536;                // 16*80*64 = 81920 bf16
  __bf16* XT    = kfpT + 81920;                // 4194304 bf16
  __bf16* qT    = XT + 4194304;                // 4194304 bf16
  __bf16* midT  = qT + 4194304;                // 4194304 bf16 (planar [bg][n][64])

  prep_kernel<<<dim3(1568), dim3(256), 0, stream>>>(Wq, Wdy, ctx, x, wqb, wdyb, kctx, XT, stats);
  kf_ln_kernel<<<dim3(196), dim3(256), 0, stream>>>(kctx, Wk, gk, bk, kf);
  kfp_kernel<<<dim3(16, 5), dim3(256), 0, stream>>>(kf, Wproj, kfpT);
  conv_mfma_kernel<0><<<dim3(32, 2, 4), dim3(256), 0, stream>>>(wqb, XT, qT, stats, nullptr, nullptr);
  attn_kernel<<<dim3(16, 32), dim3(256), 0, stream>>>(qT, stats, gq, bq, kfpT, rpb1, rpb2, attnL);
  na2d_kernel<<<dim3(16, 16, 2), dim3(256), 0, stream>>>(attnL, XT, midT);
  conv_mfma_kernel<1><<<dim3(32, 2, 4), dim3(256), 0, stream>>>(wdyb, midT, out, nullptr, bn_g, bn_b);
}